// Round 7
// baseline (318.171 us; speedup 1.0000x reference)
//
#include <hip/hip_runtime.h>

// ImportanceAggregator pipeline:
//   K0 convert_all : feat fp32 -> featb bf16 (row-major) and W -> wtp bf16.
//   K1 pool_b      : PROVEN gather (56 us, per-XCD L2-fill floor). The
//                    XCD-slicing arc (R2-R6) cut FETCH 175->37 MB but never
//                    beat 56 us (latency-exposed gathers, 62-108 us) ->
//                    closed by pre-committed gate; reverted for good.
//   K2 gemm_lnr    : NEW. B (128 KB) resident in LDS, staged ONCE per block;
//                    256 blocks x 384 thr (~157 KB LDS -> 1 block/CU, 6
//                    waves). Each wave independently grid-strides 16-row
//                    tiles: 8 aF loads, 128 ds_read_b128 + 128 MFMA, LN,
//                    store. NO steady-state barriers, no per-block B
//                    re-streaming (old: 782 blocks x 128 KB from L2 with a
//                    vmcnt-drain barrier per chunk = m97 stall pattern).
//                    Math/fragment layouts identical to proven gemm_ln.
// Ledger: total - pool = ~129 us constant (R0/R2/R5/R6); convert+gemm each
// bounded < 55.7 us by top-5; rooflines are 12/15 us -> this round splits
// hypothesis A (gemm ~50, fixable) vs B (overhead; target convert next).
// R4 LESSON (rigor): aggb scratch MUST NOT live in d_out (replay-poison
// race). aggb lives in d_ws (astr=256); d_out is write-only on main path.
// Lessons pinned: no 64-thread blocks (R6); no hoisted runtime-indexed
// arrays (R4); float4 epilogue (R3/R5); launch_bounds min-waves = VGPR cap
// -> spill (R7); natural alloc (R8); nt needs ext_vector types (R1); >=8
// loads in flight (R2); interleaved slices share lines -> thrash (R3);
// shfl in address path serializes gathers (R5); L2-residency cuts FETCH
// but not time when gathers are latency-exposed (R6).

#define NN   50000
#define KNB  16
#define D    256
#define WSTR 272     // epilogue slab stride (floats): 272%32=16 -> 2-way alias = free
#define GWAVES 6     // waves per gemm_lnr block (384 threads)

typedef __attribute__((ext_vector_type(8))) short short8;   // 8 x bf16 (4 VGPRs)
typedef __attribute__((ext_vector_type(4))) float f32x4;

static __device__ __forceinline__ unsigned short f2bf(float x) {
    unsigned int u = __float_as_uint(x);
    return (unsigned short)((u + 0x7FFFu + ((u >> 16) & 1u)) >> 16);  // RNE
}
static __device__ __forceinline__ float bf2f(unsigned short h) {
    return __uint_as_float((unsigned int)h << 16);
}

// ---------------- K0: both conversions in one dispatch --------------------
// blocks [0,nfb): feat fp32 -> featb bf16 row-major (8 elem/thread).
// blocks [nfb,nfb+32): W -> bf16 packed kb-major: frag g=(kb*16+c)*64+lane
//   holds B[k = kb*32 + (lane>>4)*8 + j][n = c*16 + (lane&15)].
__global__ __launch_bounds__(256) void convert_all(const float* __restrict__ feat,
                                                   const float* __restrict__ Wm,
                                                   unsigned short* __restrict__ featb,
                                                   unsigned short* __restrict__ wtp,
                                                   int nfb) {
    if ((int)blockIdx.x < nfb) {
        const size_t g = (size_t)blockIdx.x * 256 + threadIdx.x;
        const float4 a = *(const float4*)(feat + g * 8);
        const float4 b = *(const float4*)(feat + g * 8 + 4);
        short8 o;
        o[0] = (short)f2bf(a.x); o[1] = (short)f2bf(a.y);
        o[2] = (short)f2bf(a.z); o[3] = (short)f2bf(a.w);
        o[4] = (short)f2bf(b.x); o[5] = (short)f2bf(b.y);
        o[6] = (short)f2bf(b.z); o[7] = (short)f2bf(b.w);
        *(short8*)(featb + g * 8) = o;
    } else {
        const int g    = (blockIdx.x - nfb) * 256 + threadIdx.x;    // 0..8191
        const int lane = g & 63;
        const int c    = (g >> 6) & 15;
        const int kb   = g >> 10;
        const int n    = c * 16 + (lane & 15);
        const int k0   = kb * 32 + (lane >> 4) * 8;
        short8 v;
        #pragma unroll
        for (int j = 0; j < 8; ++j) v[j] = (short)f2bf(Wm[(size_t)(k0 + j) * D + n]);
        *(short8*)(wtp + (size_t)g * 8) = v;
    }
}

// ---------------- K1: pool_b, proven gather (row-major featb) -------------
__global__ __launch_bounds__(256, 8) void pool_b(const unsigned short* __restrict__ featb,
                                                 const int*   __restrict__ nbr,
                                                 const float* __restrict__ iw,
                                                 unsigned short* __restrict__ aggb,
                                                 int astr) {
    const int  t    = threadIdx.x;
    const int  lane = t & 63;
    const int  wq   = t >> 6;
    const long n    = (long)blockIdx.x * 4 + wq;   // one wave per node

    float ws = 0.f;
    #pragma unroll
    for (int k = 0; k < KNB; ++k) ws += iw[n * KNB + k];
    const bool  zs  = (ws == 0.f);
    const float inv = zs ? (1.f / KNB) : (1.f / ws);

    float4 p = make_float4(0.f, 0.f, 0.f, 0.f);
    #pragma unroll 1
    for (int kb = 0; kb < KNB; kb += 8) {          // 8 gathers in flight
        int   idx[8];
        float w[8];
        #pragma unroll
        for (int k = 0; k < 8; ++k) {
            idx[k] = nbr[n * KNB + kb + k];
            w[k]   = iw [n * KNB + kb + k];
        }
        #pragma unroll
        for (int k = 0; k < 8; ++k) {
            const float   wk = zs ? inv : (w[k] * inv);
            const ushort4 u  = *(const ushort4*)(featb + (size_t)idx[k] * D + lane * 4);
            p.x += wk * bf2f(u.x); p.y += wk * bf2f(u.y);
            p.z += wk * bf2f(u.z); p.w += wk * bf2f(u.w);
        }
    }
    ushort4 o;
    o.x = f2bf(p.x); o.y = f2bf(p.y); o.z = f2bf(p.z); o.w = f2bf(p.w);
    *(ushort4*)(aggb + (size_t)n * astr + lane * 4) = o;
}

// Fallback (ws too small for featb): fp32 gathers, one wave per node.
__global__ __launch_bounds__(256, 8) void pool_f(const float* __restrict__ feat,
                                                 const int*   __restrict__ nbr,
                                                 const float* __restrict__ iw,
                                                 unsigned short* __restrict__ aggb,
                                                 int astr) {
    const int  t    = threadIdx.x;
    const int  lane = t & 63;
    const int  wq   = t >> 6;
    const long n    = (long)blockIdx.x * 4 + wq;
    float ws = 0.f;
    #pragma unroll
    for (int k = 0; k < KNB; ++k) ws += iw[n * KNB + k];
    const bool  zs  = (ws == 0.f);
    const float inv = zs ? (1.f / KNB) : (1.f / ws);
    float4 p = make_float4(0.f, 0.f, 0.f, 0.f);
    #pragma unroll 1
    for (int kb = 0; kb < KNB; kb += 8) {
        int idx[8]; float w[8];
        #pragma unroll
        for (int k = 0; k < 8; ++k) { idx[k] = nbr[n*KNB+kb+k]; w[k] = iw[n*KNB+kb+k]; }
        #pragma unroll
        for (int k = 0; k < 8; ++k) {
            const float  wk = zs ? inv : (w[k] * inv);
            const float4 f  = *(const float4*)(feat + (size_t)idx[k] * D + lane * 4);
            p.x += wk*f.x; p.y += wk*f.y; p.z += wk*f.z; p.w += wk*f.w;
        }
    }
    ushort4 o;
    o.x = f2bf(p.x); o.y = f2bf(p.y); o.z = f2bf(p.z); o.w = f2bf(p.w);
    *(ushort4*)(aggb + (size_t)n * astr + lane * 4) = o;
}

// ---------------- K2 (new): resident-B GEMM + LayerNorm -------------------
// 256 blocks x 384 threads. sB = entire B (128 KB) staged once; one barrier;
// then each wave grid-strides independent 16-row tiles, no further syncs.
// Per tile per wave: 8 x 16 B aF loads (independent), 8 kb x 16 c
// { ds_read_b128 (conflict-free) + mfma_16x16x32 }, LN epilogue via
// per-wave LDS slab transpose, coalesced float4 stores.
__global__ __launch_bounds__(384) void gemm_lnr(const unsigned short* __restrict__ aggb,
                                                int astr,
                                                const unsigned short* __restrict__ wtp,
                                                const float* __restrict__ bias,
                                                const float* __restrict__ gamma,
                                                const float* __restrict__ beta,
                                                float* __restrict__ out) {
    __shared__ short sB[65536];                     // full B: 128 KB
    __shared__ float fsh[GWAVES][4 * WSTR];         // 26.1 KB epilogue slabs

    const int t    = threadIdx.x;
    const int lane = t & 63;
    const int w    = t >> 6;
    const int quad = lane >> 4;
    const int l15  = lane & 15;

    // Stage all of B once (128 KB from L2-hot wtp; ~22 short8 per thread).
    const short8* wv  = (const short8*)wtp;         // frag u of chunk kb: wv[kb*1024+u]
    short8*       sB8 = (short8*)sB;
    for (int u = t; u < 8192; u += 384) sB8[u] = wv[u];
    __syncthreads();                                // the only barrier

    // Tile-invariant epilogue constants.
    float bv[16];
    #pragma unroll
    for (int c = 0; c < 16; ++c) bv[c] = bias[c * 16 + l15];
    const float4 gv4 = *(const float4*)(gamma + lane * 4);
    const float4 bt4 = *(const float4*)(beta  + lane * 4);
    float* wsh = fsh[w];

    const int NT = (NN + 15) / 16;                  // 3125 row-tiles
    for (int tile = blockIdx.x * GWAVES + w; tile < NT; tile += 256 * GWAVES) {
        const int rowbase = tile * 16;
        const int arow    = min(rowbase + l15, NN - 1);
        const unsigned short* aptr = aggb + (size_t)arow * astr + quad * 8;

        short8 aF[8];                               // 8 independent 16 B loads
        #pragma unroll
        for (int kb = 0; kb < 8; ++kb) aF[kb] = *(const short8*)(aptr + kb * 32);

        f32x4 acc[16];
        #pragma unroll
        for (int c = 0; c < 16; ++c) acc[c] = (f32x4){0.f, 0.f, 0.f, 0.f};

        #pragma unroll
        for (int kb = 0; kb < 8; ++kb) {
            #pragma unroll
            for (int c = 0; c < 16; ++c) {          // conflict-free ds_read_b128
                const short8 b = sB8[kb * 1024 + c * 64 + lane];
                acc[c] = __builtin_amdgcn_mfma_f32_16x16x32_bf16(aF[kb], b, acc[c],
                                                                 0, 0, 0);
            }
        }

        #pragma unroll
        for (int j = 0; j < 4; ++j) {   // C/D: row = quad*4 + j, col = c*16 + l15
            float s = 0.f, sq = 0.f;
            #pragma unroll
            for (int c = 0; c < 16; ++c) {
                const float v = acc[c][j] + bv[c];
                s += v; sq += v * v;
            }
            #pragma unroll
            for (int off = 1; off < 16; off <<= 1) {   // reduce across l15
                s  += __shfl_xor(s,  off, 64);
                sq += __shfl_xor(sq, off, 64);
            }
            const float mean = s * (1.f / D);
            const float var  = sq * (1.f / D) - mean * mean;   // biased (torch LN)
            const float rstd = rsqrtf(var + 1e-5f);
            #pragma unroll
            for (int c = 0; c < 16; ++c)           // row quad*4+j -> slab slot quad
                wsh[quad * WSTR + c * 16 + l15] = (acc[c][j] + bv[c] - mean) * rstd;
            // same-wave LDS dependency: compiler inserts lgkmcnt wait, no barrier
            #pragma unroll
            for (int p = 0; p < 4; ++p) {          // rows {j, 4+j, 8+j, 12+j}
                const long r = rowbase + p * 4 + j;
                if (r < NN) {
                    const float4 v = *(const float4*)(wsh + p * WSTR + lane * 4);
                    float4 o;
                    o.x = v.x * gv4.x + bt4.x; o.y = v.y * gv4.y + bt4.y;
                    o.z = v.z * gv4.z + bt4.z; o.w = v.w * gv4.w + bt4.w;
                    *(float4*)(out + r * D + lane * 4) = o;   // coalesced
                }
            }
        }
    }
}

// ---------------- K2 (legacy, fallback tiers): LDS-staged-chunk GEMM ------
__global__ __launch_bounds__(256) void gemm_ln(const unsigned short* __restrict__ aggb,
                                               int astr,
                                               const unsigned short* __restrict__ wtp,
                                               const float* __restrict__ bias,
                                               const float* __restrict__ gamma,
                                               const float* __restrict__ beta,
                                               float* __restrict__ out) {
    __shared__ short sB[2][8192];
    __shared__ float fsh[4][4 * WSTR];

    const int t       = threadIdx.x;
    const int lane    = t & 63;
    const int wq      = t >> 6;
    const int quad    = lane >> 4;
    const int l15     = lane & 15;
    const int rowbase = blockIdx.x * 64 + wq * 16;

    const int arow = min(rowbase + l15, NN - 1);
    const unsigned short* aptr = aggb + (size_t)arow * astr + quad * 8;
    const short8* wv = (const short8*)wtp;

    short8 aF[8];
    #pragma unroll
    for (int kb = 0; kb < 8; ++kb) aF[kb] = *(const short8*)(aptr + kb * 32);

    #pragma unroll
    for (int i = 0; i < 4; ++i)
        *(short8*)&sB[0][(size_t)(i * 256 + t) * 8] = wv[i * 256 + t];
    __syncthreads();

    f32x4 acc[16];
    #pragma unroll
    for (int c = 0; c < 16; ++c) acc[c] = (f32x4){0.f, 0.f, 0.f, 0.f};

    #pragma unroll
    for (int kb = 0; kb < 8; ++kb) {
        const int buf = kb & 1;
        short8 stg[4];
        if (kb < 7) {
            #pragma unroll
            for (int i = 0; i < 4; ++i)
                stg[i] = wv[(size_t)(kb + 1) * 1024 + i * 256 + t];
        }
        #pragma unroll
        for (int c = 0; c < 16; ++c) {
            const short8 b = *(const short8*)&sB[buf][(size_t)(c * 64 + lane) * 8];
            acc[c] = __builtin_amdgcn_mfma_f32_16x16x32_bf16(aF[kb], b, acc[c], 0, 0, 0);
        }
        if (kb < 7) {
            #pragma unroll
            for (int i = 0; i < 4; ++i)
                *(short8*)&sB[buf ^ 1][(size_t)(i * 256 + t) * 8] = stg[i];
        }
        __syncthreads();
    }

    float bv[16];
    #pragma unroll
    for (int c = 0; c < 16; ++c) bv[c] = bias[c * 16 + l15];
    const float4 gv4 = *(const float4*)(gamma + lane * 4);
    const float4 bt4 = *(const float4*)(beta  + lane * 4);
    float* wsh = fsh[wq];

    #pragma unroll
    for (int j = 0; j < 4; ++j) {
        float s = 0.f, sq = 0.f;
        #pragma unroll
        for (int c = 0; c < 16; ++c) {
            const float v = acc[c][j] + bv[c];
            s += v; sq += v * v;
        }
        #pragma unroll
        for (int off = 1; off < 16; off <<= 1) {
            s  += __shfl_xor(s,  off, 64);
            sq += __shfl_xor(sq, off, 64);
        }
        const float mean = s * (1.f / D);
        const float var  = sq * (1.f / D) - mean * mean;
        const float rstd = rsqrtf(var + 1e-5f);
        #pragma unroll
        for (int c = 0; c < 16; ++c)
            wsh[quad * WSTR + c * 16 + l15] = (acc[c][j] + bv[c] - mean) * rstd;
        #pragma unroll
        for (int p = 0; p < 4; ++p) {
            const long r = rowbase + p * 4 + j;
            if (r < NN) {
                const float4 v = *(const float4*)(wsh + p * WSTR + lane * 4);
                float4 o;
                o.x = v.x * gv4.x + bt4.x; o.y = v.y * gv4.y + bt4.y;
                o.z = v.z * gv4.z + bt4.z; o.w = v.w * gv4.w + bt4.w;
                *(float4*)(out + r * D + lane * 4) = o;
            }
        }
    }
}

extern "C" void kernel_launch(void* const* d_in, const int* in_sizes, int n_in,
                              void* d_out, int out_size, void* d_ws, size_t ws_size,
                              hipStream_t stream) {
    const float* feat = (const float*)d_in[0];
    const int*   nbr  = (const int*)d_in[1];
    const float* iw   = (const float*)d_in[2];
    const float* Wm   = (const float*)d_in[3];
    const float* b    = (const float*)d_in[4];
    const float* g    = (const float*)d_in[5];
    const float* be   = (const float*)d_in[6];
    float*       out  = (float*)d_out;

    const size_t featB = (size_t)NN * D * 2;                         // 25.6 MB
    unsigned short* wtp    = (unsigned short*)d_ws;                  // 128 KB
    unsigned short* featb  = (unsigned short*)((char*)d_ws + 131072);
    unsigned short* aggb_w = (unsigned short*)((char*)d_ws + 131072 + featB);

    if (ws_size >= 131072 + 2 * featB) {
        // Main path: row-major featb, pool_b, aggb in d_ws (astr=256,
        // contiguous 512 B rows), resident-B gemm. d_out write-only.
        convert_all<<<dim3(6282), dim3(256), 0, stream>>>(feat, Wm, featb, wtp, 6250);
        pool_b<<<dim3(NN / 4), dim3(256), 0, stream>>>(featb, nbr, iw, aggb_w, 256);
        gemm_lnr<<<dim3(256), dim3(384), 0, stream>>>(aggb_w, 256, wtp, b, g, be, out);
    } else if (ws_size >= 131072 + featB) {
        // Legacy R0 path (dead in practice): aggb aliases d_out.
        unsigned short* aggb = (unsigned short*)d_out;
        convert_all<<<dim3(6282), dim3(256), 0, stream>>>(feat, Wm, featb, wtp, 6250);
        pool_b<<<dim3(NN / 4), dim3(256), 0, stream>>>(featb, nbr, iw, aggb, 512);
        gemm_ln<<<dim3((NN + 63) / 64), dim3(256), 0, stream>>>(
            aggb, 512, wtp, b, g, be, out);
    } else {
        unsigned short* aggb = (unsigned short*)d_out;
        convert_all<<<dim3(32), dim3(256), 0, stream>>>(feat, Wm, featb, wtp, 0);
        pool_f<<<dim3(NN / 4), dim3(256), 0, stream>>>(feat, nbr, iw, aggb, 512);
        gemm_ln<<<dim3((NN + 63) / 64), dim3(256), 0, stream>>>(
            aggb, 512, wtp, b, g, be, out);
    }
}

// Round 8
// 258.324 us; speedup vs baseline: 1.2317x; 1.2317x over previous
//
#include <hip/hip_runtime.h>

// ImportanceAggregator pipeline:
//   K0 convert_all : feat fp32 -> featb bf16 (row-major) and W -> wtp bf16.
//   K1 pool_b      : PROVEN gather (56 us, per-XCD L2-fill floor). The
//                    XCD-slicing arc (R2-R6) cut FETCH 175->37 MB but never
//                    beat 56 us (latency-exposed gathers) -> closed by gate.
//   K2 gemm_lnr    : resident-B GEMM+LN. B (128 KB) staged in LDS ONCE per
//                    block, zero steady-state barriers, waves grid-stride
//                    16-row tiles. R7 ran this at 384 thr -> compiler capped
//                    VGPR=128 -> acc[16] SPILLED (FETCH +142 MB ~= WRITE
//                    +151 MB scratch round-trip, 186 us). R8: 256 thr /
//                    4 waves (the shape proven spill-free in gemm_ln),
//                    natural VGPR, LDS 145.4 KB -> 1 block/CU, grid 256.
// Ledger (R7 closed it): old gemm_ln ~54 us, convert+overhead ~76 us,
// pool 56 us. Hypothesis A confirmed -> resident-B is the right attack.
// R4 LESSON (rigor): aggb scratch MUST NOT live in d_out (replay-poison
// race). aggb lives in d_ws (astr=256); d_out write-only on main path.
// Lessons pinned: no 64-thread blocks (R6); no hoisted runtime-indexed
// arrays (R4); float4 epilogue (R3/R5); launch_bounds min-waves = VGPR cap
// -> spill (R7); natural alloc (R8); nt needs ext_vector types (R1); >=8
// loads in flight (R2); interleaved slices share lines -> thrash (R3);
// shfl in address path serializes gathers (R5); L2-residency cuts FETCH
// not time when latency-exposed (R6); 384-thr blocks spill this tile (R7b).
// Gate: gemm_lnr > 54 us -> revert to gemm_ln for good.

#define NN   50000
#define KNB  16
#define D    256
#define WSTR 272     // epilogue slab stride (floats): 272%32=16 -> 2-way alias = free
#define GWAVES 4     // waves per gemm_lnr block (256 threads; 384 spills, R7)

typedef __attribute__((ext_vector_type(8))) short short8;   // 8 x bf16 (4 VGPRs)
typedef __attribute__((ext_vector_type(4))) float f32x4;

static __device__ __forceinline__ unsigned short f2bf(float x) {
    unsigned int u = __float_as_uint(x);
    return (unsigned short)((u + 0x7FFFu + ((u >> 16) & 1u)) >> 16);  // RNE
}
static __device__ __forceinline__ float bf2f(unsigned short h) {
    return __uint_as_float((unsigned int)h << 16);
}

// ---------------- K0: both conversions in one dispatch --------------------
// blocks [0,nfb): feat fp32 -> featb bf16 row-major (8 elem/thread).
// blocks [nfb,nfb+32): W -> bf16 packed kb-major: frag g=(kb*16+c)*64+lane
//   holds B[k = kb*32 + (lane>>4)*8 + j][n = c*16 + (lane&15)].
__global__ __launch_bounds__(256) void convert_all(const float* __restrict__ feat,
                                                   const float* __restrict__ Wm,
                                                   unsigned short* __restrict__ featb,
                                                   unsigned short* __restrict__ wtp,
                                                   int nfb) {
    if ((int)blockIdx.x < nfb) {
        const size_t g = (size_t)blockIdx.x * 256 + threadIdx.x;
        const float4 a = *(const float4*)(feat + g * 8);
        const float4 b = *(const float4*)(feat + g * 8 + 4);
        short8 o;
        o[0] = (short)f2bf(a.x); o[1] = (short)f2bf(a.y);
        o[2] = (short)f2bf(a.z); o[3] = (short)f2bf(a.w);
        o[4] = (short)f2bf(b.x); o[5] = (short)f2bf(b.y);
        o[6] = (short)f2bf(b.z); o[7] = (short)f2bf(b.w);
        *(short8*)(featb + g * 8) = o;
    } else {
        const int g    = (blockIdx.x - nfb) * 256 + threadIdx.x;    // 0..8191
        const int lane = g & 63;
        const int c    = (g >> 6) & 15;
        const int kb   = g >> 10;
        const int n    = c * 16 + (lane & 15);
        const int k0   = kb * 32 + (lane >> 4) * 8;
        short8 v;
        #pragma unroll
        for (int j = 0; j < 8; ++j) v[j] = (short)f2bf(Wm[(size_t)(k0 + j) * D + n]);
        *(short8*)(wtp + (size_t)g * 8) = v;
    }
}

// ---------------- K1: pool_b, proven gather (row-major featb) -------------
__global__ __launch_bounds__(256, 8) void pool_b(const unsigned short* __restrict__ featb,
                                                 const int*   __restrict__ nbr,
                                                 const float* __restrict__ iw,
                                                 unsigned short* __restrict__ aggb,
                                                 int astr) {
    const int  t    = threadIdx.x;
    const int  lane = t & 63;
    const int  wq   = t >> 6;
    const long n    = (long)blockIdx.x * 4 + wq;   // one wave per node

    float ws = 0.f;
    #pragma unroll
    for (int k = 0; k < KNB; ++k) ws += iw[n * KNB + k];
    const bool  zs  = (ws == 0.f);
    const float inv = zs ? (1.f / KNB) : (1.f / ws);

    float4 p = make_float4(0.f, 0.f, 0.f, 0.f);
    #pragma unroll 1
    for (int kb = 0; kb < KNB; kb += 8) {          // 8 gathers in flight
        int   idx[8];
        float w[8];
        #pragma unroll
        for (int k = 0; k < 8; ++k) {
            idx[k] = nbr[n * KNB + kb + k];
            w[k]   = iw [n * KNB + kb + k];
        }
        #pragma unroll
        for (int k = 0; k < 8; ++k) {
            const float   wk = zs ? inv : (w[k] * inv);
            const ushort4 u  = *(const ushort4*)(featb + (size_t)idx[k] * D + lane * 4);
            p.x += wk * bf2f(u.x); p.y += wk * bf2f(u.y);
            p.z += wk * bf2f(u.z); p.w += wk * bf2f(u.w);
        }
    }
    ushort4 o;
    o.x = f2bf(p.x); o.y = f2bf(p.y); o.z = f2bf(p.z); o.w = f2bf(p.w);
    *(ushort4*)(aggb + (size_t)n * astr + lane * 4) = o;
}

// Fallback (ws too small for featb): fp32 gathers, one wave per node.
__global__ __launch_bounds__(256, 8) void pool_f(const float* __restrict__ feat,
                                                 const int*   __restrict__ nbr,
                                                 const float* __restrict__ iw,
                                                 unsigned short* __restrict__ aggb,
                                                 int astr) {
    const int  t    = threadIdx.x;
    const int  lane = t & 63;
    const int  wq   = t >> 6;
    const long n    = (long)blockIdx.x * 4 + wq;
    float ws = 0.f;
    #pragma unroll
    for (int k = 0; k < KNB; ++k) ws += iw[n * KNB + k];
    const bool  zs  = (ws == 0.f);
    const float inv = zs ? (1.f / KNB) : (1.f / ws);
    float4 p = make_float4(0.f, 0.f, 0.f, 0.f);
    #pragma unroll 1
    for (int kb = 0; kb < KNB; kb += 8) {
        int idx[8]; float w[8];
        #pragma unroll
        for (int k = 0; k < 8; ++k) { idx[k] = nbr[n*KNB+kb+k]; w[k] = iw[n*KNB+kb+k]; }
        #pragma unroll
        for (int k = 0; k < 8; ++k) {
            const float  wk = zs ? inv : (w[k] * inv);
            const float4 f  = *(const float4*)(feat + (size_t)idx[k] * D + lane * 4);
            p.x += wk*f.x; p.y += wk*f.y; p.z += wk*f.z; p.w += wk*f.w;
        }
    }
    ushort4 o;
    o.x = f2bf(p.x); o.y = f2bf(p.y); o.z = f2bf(p.z); o.w = f2bf(p.w);
    *(ushort4*)(aggb + (size_t)n * astr + lane * 4) = o;
}

// ---------------- K2: resident-B GEMM + LayerNorm (256 thr, v2) -----------
// 256 blocks x 256 threads (4 waves). sB = entire B (128 KB) staged once;
// one barrier; then each wave grid-strides independent 16-row tiles with no
// further syncs. Per tile: 8 x 16 B aF loads, 8 kb x 16 c { ds_read_b128 +
// mfma_16x16x32 }, LN epilogue via per-wave LDS slab, float4 stores.
__global__ __launch_bounds__(256) void gemm_lnr(const unsigned short* __restrict__ aggb,
                                                int astr,
                                                const unsigned short* __restrict__ wtp,
                                                const float* __restrict__ bias,
                                                const float* __restrict__ gamma,
                                                const float* __restrict__ beta,
                                                float* __restrict__ out) {
    __shared__ short sB[65536];                     // full B: 128 KB
    __shared__ float fsh[GWAVES][4 * WSTR];         // 17.4 KB epilogue slabs

    const int t    = threadIdx.x;
    const int lane = t & 63;
    const int w    = t >> 6;
    const int quad = lane >> 4;
    const int l15  = lane & 15;

    // Stage all of B once (128 KB from L2-hot wtp; 32 short8 per thread).
    const short8* wv  = (const short8*)wtp;         // frag u of chunk kb: wv[kb*1024+u]
    short8*       sB8 = (short8*)sB;
    for (int u = t; u < 8192; u += 256) sB8[u] = wv[u];
    __syncthreads();                                // the only barrier

    // Tile-invariant epilogue constants.
    float bv[16];
    #pragma unroll
    for (int c = 0; c < 16; ++c) bv[c] = bias[c * 16 + l15];
    const float4 gv4 = *(const float4*)(gamma + lane * 4);
    const float4 bt4 = *(const float4*)(beta  + lane * 4);
    float* wsh = fsh[w];

    const int NT = (NN + 15) / 16;                  // 3125 row-tiles
    for (int tile = blockIdx.x * GWAVES + w; tile < NT; tile += 256 * GWAVES) {
        const int rowbase = tile * 16;
        const int arow    = min(rowbase + l15, NN - 1);
        const unsigned short* aptr = aggb + (size_t)arow * astr + quad * 8;

        short8 aF[8];                               // 8 independent 16 B loads
        #pragma unroll
        for (int kb = 0; kb < 8; ++kb) aF[kb] = *(const short8*)(aptr + kb * 32);

        f32x4 acc[16];
        #pragma unroll
        for (int c = 0; c < 16; ++c) acc[c] = (f32x4){0.f, 0.f, 0.f, 0.f};

        #pragma unroll
        for (int kb = 0; kb < 8; ++kb) {
            #pragma unroll
            for (int c = 0; c < 16; ++c) {          // conflict-free ds_read_b128
                const short8 b = sB8[kb * 1024 + c * 64 + lane];
                acc[c] = __builtin_amdgcn_mfma_f32_16x16x32_bf16(aF[kb], b, acc[c],
                                                                 0, 0, 0);
            }
        }

        #pragma unroll
        for (int j = 0; j < 4; ++j) {   // C/D: row = quad*4 + j, col = c*16 + l15
            float s = 0.f, sq = 0.f;
            #pragma unroll
            for (int c = 0; c < 16; ++c) {
                const float v = acc[c][j] + bv[c];
                s += v; sq += v * v;
            }
            #pragma unroll
            for (int off = 1; off < 16; off <<= 1) {   // reduce across l15
                s  += __shfl_xor(s,  off, 64);
                sq += __shfl_xor(sq, off, 64);
            }
            const float mean = s * (1.f / D);
            const float var  = sq * (1.f / D) - mean * mean;   // biased (torch LN)
            const float rstd = rsqrtf(var + 1e-5f);
            #pragma unroll
            for (int c = 0; c < 16; ++c)           // row quad*4+j -> slab slot quad
                wsh[quad * WSTR + c * 16 + l15] = (acc[c][j] + bv[c] - mean) * rstd;
            // same-wave LDS dependency: compiler inserts lgkmcnt wait, no barrier
            #pragma unroll
            for (int p = 0; p < 4; ++p) {          // rows {j, 4+j, 8+j, 12+j}
                const long r = rowbase + p * 4 + j;
                if (r < NN) {
                    const float4 v = *(const float4*)(wsh + p * WSTR + lane * 4);
                    float4 o;
                    o.x = v.x * gv4.x + bt4.x; o.y = v.y * gv4.y + bt4.y;
                    o.z = v.z * gv4.z + bt4.z; o.w = v.w * gv4.w + bt4.w;
                    *(float4*)(out + r * D + lane * 4) = o;   // coalesced
                }
            }
        }
    }
}

// ---------------- K2 (legacy, fallback tiers): LDS-staged-chunk GEMM ------
__global__ __launch_bounds__(256) void gemm_ln(const unsigned short* __restrict__ aggb,
                                               int astr,
                                               const unsigned short* __restrict__ wtp,
                                               const float* __restrict__ bias,
                                               const float* __restrict__ gamma,
                                               const float* __restrict__ beta,
                                               float* __restrict__ out) {
    __shared__ short sB[2][8192];
    __shared__ float fsh[4][4 * WSTR];

    const int t       = threadIdx.x;
    const int lane    = t & 63;
    const int wq      = t >> 6;
    const int quad    = lane >> 4;
    const int l15     = lane & 15;
    const int rowbase = blockIdx.x * 64 + wq * 16;

    const int arow = min(rowbase + l15, NN - 1);
    const unsigned short* aptr = aggb + (size_t)arow * astr + quad * 8;
    const short8* wv = (const short8*)wtp;

    short8 aF[8];
    #pragma unroll
    for (int kb = 0; kb < 8; ++kb) aF[kb] = *(const short8*)(aptr + kb * 32);

    #pragma unroll
    for (int i = 0; i < 4; ++i)
        *(short8*)&sB[0][(size_t)(i * 256 + t) * 8] = wv[i * 256 + t];
    __syncthreads();

    f32x4 acc[16];
    #pragma unroll
    for (int c = 0; c < 16; ++c) acc[c] = (f32x4){0.f, 0.f, 0.f, 0.f};

    #pragma unroll
    for (int kb = 0; kb < 8; ++kb) {
        const int buf = kb & 1;
        short8 stg[4];
        if (kb < 7) {
            #pragma unroll
            for (int i = 0; i < 4; ++i)
                stg[i] = wv[(size_t)(kb + 1) * 1024 + i * 256 + t];
        }
        #pragma unroll
        for (int c = 0; c < 16; ++c) {
            const short8 b = *(const short8*)&sB[buf][(size_t)(c * 64 + lane) * 8];
            acc[c] = __builtin_amdgcn_mfma_f32_16x16x32_bf16(aF[kb], b, acc[c], 0, 0, 0);
        }
        if (kb < 7) {
            #pragma unroll
            for (int i = 0; i < 4; ++i)
                *(short8*)&sB[buf ^ 1][(size_t)(i * 256 + t) * 8] = stg[i];
        }
        __syncthreads();
    }

    float bv[16];
    #pragma unroll
    for (int c = 0; c < 16; ++c) bv[c] = bias[c * 16 + l15];
    const float4 gv4 = *(const float4*)(gamma + lane * 4);
    const float4 bt4 = *(const float4*)(beta  + lane * 4);
    float* wsh = fsh[wq];

    #pragma unroll
    for (int j = 0; j < 4; ++j) {
        float s = 0.f, sq = 0.f;
        #pragma unroll
        for (int c = 0; c < 16; ++c) {
            const float v = acc[c][j] + bv[c];
            s += v; sq += v * v;
        }
        #pragma unroll
        for (int off = 1; off < 16; off <<= 1) {
            s  += __shfl_xor(s,  off, 64);
            sq += __shfl_xor(sq, off, 64);
        }
        const float mean = s * (1.f / D);
        const float var  = sq * (1.f / D) - mean * mean;
        const float rstd = rsqrtf(var + 1e-5f);
        #pragma unroll
        for (int c = 0; c < 16; ++c)
            wsh[quad * WSTR + c * 16 + l15] = (acc[c][j] + bv[c] - mean) * rstd;
        #pragma unroll
        for (int p = 0; p < 4; ++p) {
            const long r = rowbase + p * 4 + j;
            if (r < NN) {
                const float4 v = *(const float4*)(wsh + p * WSTR + lane * 4);
                float4 o;
                o.x = v.x * gv4.x + bt4.x; o.y = v.y * gv4.y + bt4.y;
                o.z = v.z * gv4.z + bt4.z; o.w = v.w * gv4.w + bt4.w;
                *(float4*)(out + r * D + lane * 4) = o;
            }
        }
    }
}

extern "C" void kernel_launch(void* const* d_in, const int* in_sizes, int n_in,
                              void* d_out, int out_size, void* d_ws, size_t ws_size,
                              hipStream_t stream) {
    const float* feat = (const float*)d_in[0];
    const int*   nbr  = (const int*)d_in[1];
    const float* iw   = (const float*)d_in[2];
    const float* Wm   = (const float*)d_in[3];
    const float* b    = (const float*)d_in[4];
    const float* g    = (const float*)d_in[5];
    const float* be   = (const float*)d_in[6];
    float*       out  = (float*)d_out;

    const size_t featB = (size_t)NN * D * 2;                         // 25.6 MB
    unsigned short* wtp    = (unsigned short*)d_ws;                  // 128 KB
    unsigned short* featb  = (unsigned short*)((char*)d_ws + 131072);
    unsigned short* aggb_w = (unsigned short*)((char*)d_ws + 131072 + featB);

    if (ws_size >= 131072 + 2 * featB) {
        // Main path: row-major featb, pool_b, aggb in d_ws (astr=256,
        // contiguous 512 B rows), resident-B gemm. d_out write-only.
        convert_all<<<dim3(6282), dim3(256), 0, stream>>>(feat, Wm, featb, wtp, 6250);
        pool_b<<<dim3(NN / 4), dim3(256), 0, stream>>>(featb, nbr, iw, aggb_w, 256);
        gemm_lnr<<<dim3(256), dim3(256), 0, stream>>>(aggb_w, 256, wtp, b, g, be, out);
    } else if (ws_size >= 131072 + featB) {
        // Legacy R0 path (dead in practice): aggb aliases d_out.
        unsigned short* aggb = (unsigned short*)d_out;
        convert_all<<<dim3(6282), dim3(256), 0, stream>>>(feat, Wm, featb, wtp, 6250);
        pool_b<<<dim3(NN / 4), dim3(256), 0, stream>>>(featb, nbr, iw, aggb, 512);
        gemm_ln<<<dim3((NN + 63) / 64), dim3(256), 0, stream>>>(
            aggb, 512, wtp, b, g, be, out);
    } else {
        unsigned short* aggb = (unsigned short*)d_out;
        convert_all<<<dim3(32), dim3(256), 0, stream>>>(feat, Wm, featb, wtp, 0);
        pool_f<<<dim3(NN / 4), dim3(256), 0, stream>>>(feat, nbr, iw, aggb, 512);
        gemm_ln<<<dim3((NN + 63) / 64), dim3(256), 0, stream>>>(
            aggb, 512, wtp, b, g, be, out);
    }
}